// Round 4
// baseline (386.581 us; speedup 1.0000x reference)
//
#include <hip/hip_runtime.h>
#include <climits>
#include <cstdint>

#define L 1000        // NUM_LABELS
#define NROWS 32768   // 64*512

// ws layout (int32 units):
//   [0,    1000)          first_row[label]  (INT_MAX if unseen)
//   [1024, 2024)          perm_final[pos]
//   [2048, 2048+32768)    evt_slot[row] = (lab<<10)|m  at first-occurrence rows, else -1

__global__ void k_init(int* __restrict__ first_row, int* __restrict__ evt_slot) {
    int i = blockIdx.x * blockDim.x + threadIdx.x;
    if (i < NROWS) evt_slot[i] = -1;
    if (i < L) first_row[i] = INT_MAX;
}

__global__ void k_first(const int* __restrict__ labels, int* __restrict__ first_row) {
    int i = blockIdx.x * blockDim.x + threadIdx.x;
    if (i < NROWS) atomicMin(&first_row[labels[i]], i);
}

// One block per label: argmax of the first-occurrence row, first-index tiebreak.
__global__ void k_argmax(const float* __restrict__ flat, const int* __restrict__ first_row,
                         int* __restrict__ evt_slot) {
    int lab = blockIdx.x;
    int row = first_row[lab];
    if (row == INT_MAX) return;
    const float* y = flat + (size_t)row * L;
    int tid = threadIdx.x;
    float bv = -INFINITY;
    int bk = 0x7fffffff;
    if (tid < 250) {                      // 250 * 4 = 1000, float4 loads
        float4 v = ((const float4*)y)[tid];
        int k = tid * 4;
        // ascending k, strict > keeps first index
        if (v.x > bv) { bv = v.x; bk = k; }
        if (v.y > bv) { bv = v.y; bk = k + 1; }
        if (v.z > bv) { bv = v.z; bk = k + 2; }
        if (v.w > bv) { bv = v.w; bk = k + 3; }
    }
    __shared__ float sv[256];
    __shared__ int   sk[256];
    sv[tid] = bv; sk[tid] = bk;
    __syncthreads();
    for (int off = 128; off > 0; off >>= 1) {
        if (tid < off) {
            float v2 = sv[tid + off]; int k2 = sk[tid + off];
            if (v2 > sv[tid] || (v2 == sv[tid] && k2 < sk[tid])) { sv[tid] = v2; sk[tid] = k2; }
        }
        __syncthreads();
    }
    if (tid == 0) evt_slot[row] = (lab << 10) | sk[0];
}

// Single block: compact events in row order, replay transpositions, emit perm.
// Replay is a 3-deep software pipeline:
//   - events i, i+1, i+2 decoded in registers; raw evt[i+3] load in flight
//     (static addresses => evt decode is OFF the critical path)
//   - pos[] speculative reads for event i+2 issued each iter BEFORE the writes,
//     patched against writes of iter i (now) and iter i+1 (next iter)
// Critical path per iter: Pm -> r -> ds_read pos[r] -> pr -> patch  (1 LDS latency)
__global__ void __launch_bounds__(1024) k_seq(const int* __restrict__ evt_slot,
                                              int* __restrict__ perm_g) {
    __shared__ int evt[1012];
    __shared__ int pos[L];
    __shared__ int scnt[1024];
    int tid = threadIdx.x;
    int base = tid * 32;                 // 1024 threads * 32 rows = 32768
    int c = 0;
    for (int j = 0; j < 32; j++) c += (evt_slot[base + j] >= 0) ? 1 : 0;
    scnt[tid] = c;
    __syncthreads();
    // Hillis-Steele inclusive scan
    for (int off = 1; off < 1024; off <<= 1) {
        int v = scnt[tid];
        int add = (tid >= off) ? scnt[tid - off] : 0;
        __syncthreads();
        scnt[tid] = v + add;
        __syncthreads();
    }
    int K = scnt[1023];
    int w = tid ? scnt[tid - 1] : 0;
    for (int j = 0; j < 32; j++) {
        int v = evt_slot[base + j];
        if (v >= 0) evt[w++] = v;        // chunks contiguous => row order preserved
    }
    if (tid < 8) evt[K + tid] = 0;       // no-op sentinels for the pipeline tail
    if (tid < L) pos[tid] = tid;         // pos = perm^{-1}, initially identity
    __syncthreads();
    if (tid == 0 && K > 0) {
        int e0 = evt[0], e1 = evt[1], e2 = evt[2];
        int m0 = e0 & 1023, lab0 = e0 >> 10;
        int m1 = e1 & 1023, lab1 = e1 >> 10;
        int m2 = e2 & 1023, lab2 = e2 >> 10;
        int Pm0 = pos[m0], Plab0 = pos[lab0];
        int Pm1 = pos[m1], Plab1 = pos[lab1];   // pre-write; patched vs writes_0 below
        int ev3 = evt[3];
        for (int i = 0; i < K; i++) {
            int r = Pm0;
            // speculative reads for event i+2 (issued BEFORE this iter's writes)
            int Pm2   = pos[m2];
            int Plab2 = pos[lab2];
            if (r != lab0) {
                int pr = pos[r];             // the one dependent read (critical path)
                pos[r]    = Plab0;
                pos[lab0] = pr;
                // patch event i+1's pair against this iter's writes
                if (m1 == r)         Pm1 = Plab0;
                else if (m1 == lab0) Pm1 = pr;
                if (lab1 == r)         Plab1 = Plab0;
                else if (lab1 == lab0) Plab1 = pr;
                // patch event i+2's freshly-issued pair likewise
                if (m2 == r)         Pm2 = Plab0;
                else if (m2 == lab0) Pm2 = pr;
                if (lab2 == r)         Plab2 = Plab0;
                else if (lab2 == lab0) Plab2 = pr;
            }
            // shift pipeline
            m0 = m1; lab0 = lab1; Pm0 = Pm1; Plab0 = Plab1;
            m1 = m2; lab1 = lab2; Pm1 = Pm2; Plab1 = Plab2;
            m2 = ev3 & 1023; lab2 = ev3 >> 10;
            ev3 = evt[i + 4];                // static address, off critical path
        }
    }
    __syncthreads();
    if (tid < L) perm_g[pos[tid]] = tid; // invert: perm[pos[v]] = v
}

// 2 rows per block IN PARALLEL (two 256-thread groups sharing the p table).
// One barrier per block; global read and write fully coalesced float4.
__global__ void __launch_bounds__(512) k_gather(const float* __restrict__ flat,
                                                const int* __restrict__ perm_g,
                                                float* __restrict__ out) {
    __shared__ __align__(16) int   p[L];
    __shared__ __align__(16) float buf[2][L];   // buf[1] offset 4000B = 16B-aligned
    int tid = threadIdx.x;
    int g = tid >> 8;            // group 0..1 -> row within block
    int t = tid & 255;           // lane-in-group
    size_t row = (size_t)blockIdx.x * 2 + g;
    const float* src = flat + row * L;
    float*       dst = out  + row * L;
    float4 v;
    if (t < 250) v = ((const float4*)src)[t];
    if (tid < 250) ((int4*)p)[tid] = ((const int4*)perm_g)[tid];
    if (t < 250) ((float4*)buf[g])[t] = v;
    __syncthreads();             // p and buf visible
    if (t < 250) {
        int j = t * 4;
        float4 o;
        o.x = buf[g][p[j + 0]];
        o.y = buf[g][p[j + 1]];
        o.z = buf[g][p[j + 2]];
        o.w = buf[g][p[j + 3]];
        ((float4*)dst)[t] = o;
    }
}

extern "C" void kernel_launch(void* const* d_in, const int* in_sizes, int n_in,
                              void* d_out, int out_size, void* d_ws, size_t ws_size,
                              hipStream_t stream) {
    const float* flat   = (const float*)d_in[0];   // (64,512,1000) fp32
    const int*   labels = (const int*)d_in[1];     // (64,512) int32
    float* out = (float*)d_out;
    int* ws = (int*)d_ws;
    int* first_row = ws;          // 1000
    int* perm_g    = ws + 1024;   // 1000
    int* evt_slot  = ws + 2048;   // 32768

    k_init  <<<(NROWS + 255) / 256, 256, 0, stream>>>(first_row, evt_slot);
    k_first <<<(NROWS + 255) / 256, 256, 0, stream>>>(labels, first_row);
    k_argmax<<<L, 256, 0, stream>>>(flat, first_row, evt_slot);
    k_seq   <<<1, 1024, 0, stream>>>(evt_slot, perm_g);
    k_gather<<<NROWS / 2, 512, 0, stream>>>(flat, perm_g, out);
}